// Round 1
// baseline (45146.664 us; speedup 1.0000x reference)
//
#include <hip/hip_runtime.h>
#include <math.h>

#define LSEQ 512
#define BATCH 64
#define HID 1024
#define NCH 8
#define GSZ 4112

typedef __bf16 bf16x8 __attribute__((ext_vector_type(8)));
typedef float f32x4 __attribute__((ext_vector_type(4)));

__device__ __forceinline__ ushort f2b(float f) {
  union { float f; unsigned u; } v; v.f = f;
  unsigned u = v.u;
  unsigned r = (u + 0x7FFFu + ((u >> 16) & 1u)) >> 16;  // RNE
  return (ushort)r;
}

// ---- transpose + cast: W (K x N) f32 -> WT (N x K) bf16 ----
__global__ __launch_bounds__(256) void k_transpose_cast(
    const float* __restrict__ W, ushort* __restrict__ WT, int K, int N) {
  __shared__ float tile[32][33];
  int n0 = blockIdx.x * 32, k0 = blockIdx.y * 32;
  int tx = threadIdx.x & 31, ty = threadIdx.x >> 5;
  #pragma unroll
  for (int i = ty; i < 32; i += 8) {
    int n = n0 + tx;
    tile[i][tx] = (n < N) ? W[(size_t)(k0 + i) * N + n] : 0.f;
  }
  __syncthreads();
  #pragma unroll
  for (int i = ty; i < 32; i += 8) {
    int n = n0 + i;
    if (n < N) WT[(size_t)n * K + k0 + tx] = f2b(tile[tx][i]);
  }
}

// ---- f32 -> bf16 cast (vectorized x4) ----
__global__ void k_cast4(const float4* __restrict__ in, ushort* __restrict__ out, int count4) {
  int stride = gridDim.x * blockDim.x;
  for (int i = blockIdx.x * blockDim.x + threadIdx.x; i < count4; i += stride) {
    float4 v = in[i];
    ushort4 o;
    o.x = f2b(v.x); o.y = f2b(v.y); o.z = f2b(v.z); o.w = f2b(v.w);
    *reinterpret_cast<ushort4*>(out + (size_t)i * 4) = o;
  }
}

__global__ void k_init_state(const float* __restrict__ h0l, const float* __restrict__ c0l,
                             ushort* __restrict__ hb, float* __restrict__ c, int count) {
  int i = blockIdx.x * blockDim.x + threadIdx.x;
  if (i < count) { hb[i] = f2b(h0l[i]); c[i] = c0l[i]; }
}

// C[M x N](f32) = A[M x K](bf16) @ BT[N x K](bf16)^T + bias[N] (+ extra[M x N])
// Tile: 64(M) x 64(N) per block, 4 waves (one 16-row band each), MFMA 16x16x32 bf16.
// No LDS: A-frag and B-frag are contiguous 16B per lane, L2-served.
__global__ __launch_bounds__(256) void k_gemm(
    const ushort* __restrict__ A, const ushort* __restrict__ BT,
    const float* __restrict__ bias, const float* __restrict__ extra,
    float* __restrict__ C, int K, int N) {
  int col0 = blockIdx.x * 64;
  int row0 = blockIdx.y * 64;
  int lane = threadIdx.x & 63;
  int w = threadIdx.x >> 6;
  int l15 = lane & 15;
  int koff = (lane >> 4) * 8;
  const ushort* Ap = A + (size_t)(row0 + w * 16 + l15) * K + koff;
  const ushort* Bp[4];
  int cols[4];
  #pragma unroll
  for (int cg = 0; cg < 4; ++cg) {
    int c_ = col0 + cg * 16 + l15;
    cols[cg] = c_;
    int cc = c_ < N ? c_ : N - 1;  // clamp: avoid OOB reads on partial N tile
    Bp[cg] = BT + (size_t)cc * K + koff;
  }
  f32x4 acc[4] = {};
  #pragma unroll 2
  for (int kk = 0; kk < K; kk += 32) {
    bf16x8 a = *reinterpret_cast<const bf16x8*>(Ap + kk);
    #pragma unroll
    for (int cg = 0; cg < 4; ++cg) {
      bf16x8 b = *reinterpret_cast<const bf16x8*>(Bp[cg] + kk);
      acc[cg] = __builtin_amdgcn_mfma_f32_16x16x32_bf16(a, b, acc[cg], 0, 0, 0);
    }
  }
  // C/D layout (verified m89): col = lane&15, row = (lane>>4)*4 + i
  int crow = row0 + w * 16 + (lane >> 4) * 4;
  #pragma unroll
  for (int cg = 0; cg < 4; ++cg) {
    int c_ = cols[cg];
    if (c_ >= N) continue;
    float bv = bias[c_];
    #pragma unroll
    for (int i = 0; i < 4; ++i) {
      size_t idx = (size_t)(crow + i) * N + c_;
      float v = acc[cg][i] + bv;
      if (extra) v += extra[idx];
      C[idx] = v;
    }
  }
}

// ---- ONLSTM cell update: one block per batch row ----
__global__ __launch_bounds__(128) void k_cell(
    const float* __restrict__ gates,  // 64 x GSZ
    float* __restrict__ c_state,      // 64 x 1024 (fp32, in/out)
    ushort* __restrict__ h_bf16,      // 64 x 1024 (out, next-step GEMM A)
    float* __restrict__ out_hs,       // outs[l,t] base (+ b*1024 + idx)
    float* __restrict__ out_hs2,      // output region (layer 1) or null
    float* __restrict__ dfs,          // + b
    float* __restrict__ dins,         // + b
    float* __restrict__ hT,           // or null (last step)
    float* __restrict__ cT) {         // or null
  int b = blockIdx.x;
  int tid = threadIdx.x;
  const float* g = gates + (size_t)b * GSZ;

  // cumsoftmax over first 2*NCH logits (redundant per thread; 16 broadcast reads)
  float pi[NCH], pf[NCH];
  float m1 = -1e30f, m2 = -1e30f;
  #pragma unroll
  for (int i = 0; i < NCH; ++i) { m1 = fmaxf(m1, g[i]); m2 = fmaxf(m2, g[NCH + i]); }
  float s1 = 0.f, s2 = 0.f;
  #pragma unroll
  for (int i = 0; i < NCH; ++i) {
    pi[i] = expf(g[i] - m1); s1 += pi[i];
    pf[i] = expf(g[NCH + i] - m2); s2 += pf[i];
  }
  float cing[NCH], cfg[NCH];
  float cum1 = 0.f, cum2 = 0.f, sumin = 0.f, sumfg = 0.f;
  #pragma unroll
  for (int i = 0; i < NCH; ++i) {
    cum1 += pi[i] / s1; cing[i] = 1.f - cum1; sumin += cing[i];
    cum2 += pf[i] / s2; cfg[i] = cum2; sumfg += cfg[i];
  }
  float d_in = sumin / (float)NCH;
  float d_forget = 1.f - sumfg / (float)NCH;

  #pragma unroll
  for (int r = 0; r < 8; ++r) {
    int idx = tid + r * 128;        // n = r (chunk), k = tid
    float go = g[16 + idx];          // outg
    float gc = g[16 + 1024 + idx];   // cell
    float gi = g[16 + 2048 + idx];   // ing
    float gf = g[16 + 3072 + idx];   // fg
    float ov = cfg[r] * cing[r];
    float sgf = 1.f / (1.f + expf(-gf));
    float sgi = 1.f / (1.f + expf(-gi));
    float f_ = sgf * ov + (cfg[r] - ov);
    float i_ = sgi * ov + (cing[r] - ov);
    float cx = c_state[b * 1024 + idx];
    float cy = f_ * cx + i_ * tanhf(gc);
    float hy = (1.f / (1.f + expf(-go))) * tanhf(cy);
    c_state[b * 1024 + idx] = cy;
    h_bf16[b * 1024 + idx] = f2b(hy);
    out_hs[b * 1024 + idx] = hy;
    if (out_hs2) out_hs2[b * 1024 + idx] = hy;
    if (cT) { cT[b * 1024 + idx] = cy; hT[b * 1024 + idx] = hy; }
  }
  if (tid == 0) { dfs[b] = d_forget; dins[b] = d_in; }
}

extern "C" void kernel_launch(void* const* d_in, const int* in_sizes, int n_in,
                              void* d_out, int out_size, void* d_ws, size_t ws_size,
                              hipStream_t stream) {
  const float* x   = (const float*)d_in[0];
  const float* h0  = (const float*)d_in[1];
  const float* c0  = (const float*)d_in[2];
  const float* Wih = (const float*)d_in[3];
  const float* bih = (const float*)d_in[4];
  const float* Whh = (const float*)d_in[5];
  const float* bhh = (const float*)d_in[6];
  float* out = (float*)d_out;

  // output layout (floats)
  const size_t OFF_OUTPUT = 0;                               // (512,64,1024)
  const size_t OFF_HT   = 33554432;                          // (2,64,1024)
  const size_t OFF_CT   = OFF_HT + 131072;                   // (2,64,8,128)
  const size_t OFF_OUTS = OFF_CT + 131072;                   // (2,512,64,1024)
  const size_t OFF_DFS  = OFF_OUTS + 67108864;               // (2,512,64)
  const size_t OFF_DINS = OFF_DFS + 65536;                   // (2,512,64)

  // ---- workspace layout ----
  uint8_t* ws = (uint8_t*)d_ws;
  size_t off = 0;
  auto alloc = [&](size_t bytes) { size_t p = off; off = (off + bytes + 255) & ~(size_t)255; return p; };
  const size_t wT_sz = (size_t)GSZ * HID * 2;
  size_t o_WihT[2], o_WhhT[2];
  o_WihT[0] = alloc(wT_sz); o_WihT[1] = alloc(wT_sz);
  o_WhhT[0] = alloc(wT_sz); o_WhhT[1] = alloc(wT_sz);
  size_t o_hb    = alloc((size_t)BATCH * HID * 2);
  size_t o_c     = alloc((size_t)BATCH * HID * 4);
  size_t o_gates = alloc((size_t)BATCH * GSZ * 4);
  size_t fixed = off;
  const size_t unit = (size_t)BATCH * HID * 2 + (size_t)BATCH * GSZ * 4 + 512;
  int TC = 128;  // cap at 128 so the t_in chunk stays LLC-resident
  while (TC > 1 && fixed + (size_t)TC * unit > ws_size) TC >>= 1;
  size_t o_prevb = alloc((size_t)TC * BATCH * HID * 2);
  size_t o_tin   = alloc((size_t)TC * BATCH * GSZ * 4);

  ushort* hb    = (ushort*)(ws + o_hb);
  float*  cst   = (float*)(ws + o_c);
  float*  gates = (float*)(ws + o_gates);
  ushort* prevb = (ushort*)(ws + o_prevb);
  float*  tin   = (float*)(ws + o_tin);

  // ---- transpose-cast the 4 weight matrices (K=HID, N=GSZ) ----
  dim3 tgrid((GSZ + 31) / 32, HID / 32);
  for (int l = 0; l < 2; ++l) {
    k_transpose_cast<<<tgrid, 256, 0, stream>>>(Wih + (size_t)l * HID * GSZ,
                                                (ushort*)(ws + o_WihT[l]), HID, GSZ);
    k_transpose_cast<<<tgrid, 256, 0, stream>>>(Whh + (size_t)l * HID * GSZ,
                                                (ushort*)(ws + o_WhhT[l]), HID, GSZ);
  }

  const int NB = (GSZ + 63) / 64;  // 65 N-tiles
  for (int l = 0; l < 2; ++l) {
    const float* prev = (l == 0) ? x : (out + OFF_OUTS);  // layer-0 hs lives in outs[0]
    const ushort* WihT = (const ushort*)(ws + o_WihT[l]);
    const ushort* WhhT = (const ushort*)(ws + o_WhhT[l]);

    k_init_state<<<256, 256, 0, stream>>>(h0 + (size_t)l * BATCH * HID,
                                          c0 + (size_t)l * BATCH * HID,
                                          hb, cst, BATCH * HID);

    for (int t0 = 0; t0 < LSEQ; t0 += TC) {
      // cast this chunk of prev to bf16
      int count4 = TC * BATCH * HID / 4;
      int cblocks = (count4 + 255) / 256; if (cblocks > 2048) cblocks = 2048;
      k_cast4<<<cblocks, 256, 0, stream>>>(
          (const float4*)(prev + (size_t)t0 * BATCH * HID), prevb, count4);

      // t_in chunk GEMM: M = TC*64
      k_gemm<<<dim3(NB, TC), 256, 0, stream>>>(prevb, WihT, bih + (size_t)l * GSZ,
                                               nullptr, tin, HID, GSZ);

      for (int tt = 0; tt < TC; ++tt) {
        int t = t0 + tt;
        // gates = h @ Whh + bhh + t_in[t]
        k_gemm<<<dim3(NB, 1), 256, 0, stream>>>(hb, WhhT, bhh + (size_t)l * GSZ,
                                                tin + (size_t)tt * BATCH * GSZ,
                                                gates, HID, GSZ);
        float* hTp = nullptr; float* cTp = nullptr;
        if (t == LSEQ - 1) {
          hTp = out + OFF_HT + (size_t)l * BATCH * HID;
          cTp = out + OFF_CT + (size_t)l * BATCH * HID;
        }
        float* hs2 = (l == 1) ? (out + OFF_OUTPUT + (size_t)t * BATCH * HID) : nullptr;
        k_cell<<<BATCH, 128, 0, stream>>>(
            gates, cst, hb,
            out + OFF_OUTS + ((size_t)l * LSEQ + t) * BATCH * HID, hs2,
            out + OFF_DFS + ((size_t)l * LSEQ + t) * BATCH,
            out + OFF_DINS + ((size_t)l * LSEQ + t) * BATCH,
            hTp, cTp);
      }
    }
  }
}